// Round 6
// baseline (168.547 us; speedup 1.0000x reference)
//
#include <hip/hip_runtime.h>
#include <hip/hip_bf16.h>

#define K_DIM 1024
#define M_DIM 4096
#define N_DIM 8192
#define BK 64
#define BM 128
#define BN 128
#define NT 16

typedef __attribute__((ext_vector_type(8))) __bf16 bf16x8_t;
typedef __attribute__((ext_vector_type(16))) float f32x16;

__device__ inline unsigned short f2bf(float f) {
    unsigned u = __float_as_uint(f);
    u += 0x7FFF + ((u >> 16) & 1);   // round-to-nearest-even
    return (unsigned short)(u >> 16);
}

__device__ __forceinline__ void gload_lds16(const void* g, void* l) {
    __builtin_amdgcn_global_load_lds(
        (const __attribute__((address_space(1))) unsigned int*)g,
        (__attribute__((address_space(3))) unsigned int*)l, 16, 0, 0);
}

// softmax over 1024 cols for wa (blocks 0..4095) and wb (blocks 4096..8191)
__global__ void dual_softmax_kernel(const float* __restrict__ wa,
                                    const float* __restrict__ wb,
                                    unsigned short* __restrict__ pa,
                                    unsigned short* __restrict__ pb) {
    const int idx = blockIdx.x;
    const float* w = (idx < M_DIM) ? wa : wb;
    unsigned short* o = (idx < M_DIM) ? pa : pb;
    const int row = idx & (M_DIM - 1);
    const int tid = threadIdx.x;
    const float4 v = reinterpret_cast<const float4*>(w + (size_t)row * K_DIM)[tid];
    float m = fmaxf(fmaxf(v.x, v.y), fmaxf(v.z, v.w));
    #pragma unroll
    for (int off = 32; off >= 1; off >>= 1) m = fmaxf(m, __shfl_xor(m, off));
    __shared__ float redm[4];
    __shared__ float reds[4];
    if ((tid & 63) == 0) redm[tid >> 6] = m;
    __syncthreads();
    m = fmaxf(fmaxf(redm[0], redm[1]), fmaxf(redm[2], redm[3]));
    const float e0 = __expf(v.x - m), e1 = __expf(v.y - m);
    const float e2 = __expf(v.z - m), e3 = __expf(v.w - m);
    float s = e0 + e1 + e2 + e3;
    #pragma unroll
    for (int off = 32; off >= 1; off >>= 1) s += __shfl_xor(s, off);
    if ((tid & 63) == 0) reds[tid >> 6] = s;
    __syncthreads();
    s = reds[0] + reds[1] + reds[2] + reds[3];
    const float inv = 1.0f / s;
    ushort4 r;
    r.x = f2bf(e0 * inv); r.y = f2bf(e1 * inv);
    r.z = f2bf(e2 * inv); r.w = f2bf(e3 * inv);
    reinterpret_cast<ushort4*>(o + (size_t)row * K_DIM)[tid] = r;
}

// prev (K x N, f32) -> prevT (N x K, bf16)
__global__ void transpose_conv_kernel(const float* __restrict__ src,
                                      unsigned short* __restrict__ dst) {
    __shared__ float t[32][33];
    const int n0 = blockIdx.x * 32;
    const int k0 = blockIdx.y * 32;
    const int tx = threadIdx.x, ty = threadIdx.y;   // 32 x 8
    #pragma unroll
    for (int i = ty; i < 32; i += 8)
        t[i][tx] = src[(size_t)(k0 + i) * N_DIM + n0 + tx];
    __syncthreads();
    #pragma unroll
    for (int i = ty; i < 32; i += 8)
        dst[(size_t)(n0 + i) * K_DIM + k0 + tx] = f2bf(t[tx][i]);
}

__global__ void coef_kernel(const float* __restrict__ tw,
                            float4* __restrict__ coef) {
    const int r = blockIdx.x * 256 + threadIdx.x;
    float p[16];
    float m = -1e30f;
    #pragma unroll
    for (int k = 0; k < 16; ++k) { p[k] = tw[k * M_DIM + r]; m = fmaxf(m, p[k]); }
    float s = 0.f;
    #pragma unroll
    for (int k = 0; k < 16; ++k) { p[k] = __expf(p[k] - m); s += p[k]; }
    const float inv = 1.f / s;
    #pragma unroll
    for (int k = 0; k < 16; ++k) p[k] *= inv;
    const float cA  = p[2]+p[3]+p[6]+p[7]-p[8]-p[9]-p[12]-p[13];
    const float cB  = p[4]+p[5]+p[6]+p[7]-p[8]-p[9]-p[10]-p[11];
    const float cAB = p[1]-p[2]-p[4]-2.f*p[6]-p[7]+p[8]+2.f*p[9]+p[11]+p[13]-p[14];
    const float c0  = p[8]+p[9]+p[10]+p[11]+p[12]+p[13]+p[14]+p[15];
    coef[r] = make_float4(cA, cB, cAB, c0);
}

// Fused dual GEMM, 128x128 tile, BK=64, 4 waves (2x2, 64x64 each),
// 32x32x16 MFMA (2x2 frags per GEMM per wave), single-buffered 48 KB LDS,
// 2 blocks/CU co-resident (m114 overlap). Both-sides XOR swizzle:
// LDS(row, c16) = G(row, c16 ^ (row&7)); ds_read applies same XOR.
__global__ __launch_bounds__(256, 2)
void dual_gemm_kernel(const unsigned short* __restrict__ pa,
                      const unsigned short* __restrict__ pb,
                      const unsigned short* __restrict__ pv,
                      const float4* __restrict__ coef,
                      float* __restrict__ out) {
    __shared__ unsigned short sA[BM * BK];   // 16 KB
    __shared__ unsigned short sB[BM * BK];
    __shared__ unsigned short sP[BN * BK];

    const int tid = threadIdx.x;
    const int lane = tid & 63;
    const int w = tid >> 6;            // 0..3
    const int wm = w >> 1, wn = w & 1; // 2x2 wave grid, 64x64 each
    const int bm = blockIdx.y, bn = blockIdx.x;

    const int sub_row = lane >> 3;                // 0..7
    const int scol16  = (lane & 7) ^ sub_row;     // pre-swizzled src 16B col

    // loop-carried staging pointers (advance +128 B per K-tile)
    const char* srcA = (const char*)pa +
        ((size_t)(bm * BM + w * 32 + sub_row) * K_DIM) * 2 + scol16 * 16;
    const char* srcB = (const char*)pb +
        ((size_t)(bm * BM + w * 32 + sub_row) * K_DIM) * 2 + scol16 * 16;
    const char* srcP = (const char*)pv +
        ((size_t)(bn * BN + w * 32 + sub_row) * K_DIM) * 2 + scol16 * 16;

    const int l31 = lane & 31;
    const int kh  = lane >> 5;         // k-half for 32x32x16 operands
    const int arow0 = wm * 64 + l31;
    const int prow0 = wn * 64 + l31;

    f32x16 accA[2][2], accB[2][2];
    #pragma unroll
    for (int i = 0; i < 2; ++i)
        #pragma unroll
        for (int j = 0; j < 2; ++j)
            #pragma unroll
            for (int e = 0; e < 16; ++e) { accA[i][j][e] = 0.f; accB[i][j][e] = 0.f; }

    for (int t = 0; t < NT; ++t) {
        __syncthreads();
        // stage 12 chunks: each chunk = 8 rows x 128 B, wave w owns rows [w*32, w*32+32)
        #pragma unroll
        for (int j = 0; j < 4; ++j) {
            const int c = w * 4 + j;
            gload_lds16(srcA + j * (8 * K_DIM * 2), (char*)sA + c * 1024);
            gload_lds16(srcB + j * (8 * K_DIM * 2), (char*)sB + c * 1024);
            gload_lds16(srcP + j * (8 * K_DIM * 2), (char*)sP + c * 1024);
        }
        __syncthreads();   // drains vmcnt(0) + makes stage visible
        srcA += BK * 2; srcB += BK * 2; srcP += BK * 2;

        #pragma unroll
        for (int kk = 0; kk < 4; ++kk) {
            bf16x8_t af[2], bfv[2], pf[2];
            #pragma unroll
            for (int mi = 0; mi < 2; ++mi) {
                const int row  = arow0 + mi * 32;
                const int byte = row * 128 + (((kk * 2 + kh) ^ (row & 7)) * 16);
                af[mi]  = *reinterpret_cast<const bf16x8_t*>((const char*)sA + byte);
                bfv[mi] = *reinterpret_cast<const bf16x8_t*>((const char*)sB + byte);
            }
            #pragma unroll
            for (int ni = 0; ni < 2; ++ni) {
                const int row  = prow0 + ni * 32;
                const int byte = row * 128 + (((kk * 2 + kh) ^ (row & 7)) * 16);
                pf[ni] = *reinterpret_cast<const bf16x8_t*>((const char*)sP + byte);
            }
            #pragma unroll
            for (int mi = 0; mi < 2; ++mi)
                #pragma unroll
                for (int ni = 0; ni < 2; ++ni) {
                    accA[mi][ni] = __builtin_amdgcn_mfma_f32_32x32x16_bf16(
                        af[mi], pf[ni], accA[mi][ni], 0, 0, 0);
                    accB[mi][ni] = __builtin_amdgcn_mfma_f32_32x32x16_bf16(
                        bfv[mi], pf[ni], accB[mi][ni], 0, 0, 0);
                }
        }
    }

    // epilogue: 32x32 D layout col=lane&31, row=(reg&3)+8*(reg>>2)+4*(lane>>5)
    #pragma unroll
    for (int mi = 0; mi < 2; ++mi) {
        #pragma unroll
        for (int reg = 0; reg < 16; ++reg) {
            const int r = bm * BM + wm * 64 + mi * 32 + (reg & 3) + 8 * (reg >> 2) + 4 * kh;
            const float4 cf = coef[r];
            #pragma unroll
            for (int ni = 0; ni < 2; ++ni) {
                const int gc = bn * BN + wn * 64 + ni * 32 + l31;
                const float av = accA[mi][ni][reg];
                const float bv = accB[mi][ni][reg];
                out[(size_t)r * N_DIM + gc] =
                    fmaf(cf.z, av * bv, fmaf(cf.x, av, fmaf(cf.y, bv, cf.w)));
            }
        }
    }
}

extern "C" void kernel_launch(void* const* d_in, const int* in_sizes, int n_in,
                              void* d_out, int out_size, void* d_ws, size_t ws_size,
                              hipStream_t stream) {
    const float* prev = (const float*)d_in[0];   // (1024, 8192)
    const float* wa   = (const float*)d_in[1];   // (4096, 1024)
    const float* wb   = (const float*)d_in[2];   // (4096, 1024)
    const float* tw   = (const float*)d_in[3];   // (16, 4096)
    float* out = (float*)d_out;                  // (4096, 8192)

    char* ws = (char*)d_ws;
    unsigned short* pa = (unsigned short*)ws;                        // 8 MB
    unsigned short* pb = (unsigned short*)(ws + 8388608);            // 8 MB
    unsigned short* pv = (unsigned short*)(ws + 16777216);           // 16 MB
    float4* coef       = (float4*)(ws + 33554432);                   // 64 KB

    dual_softmax_kernel<<<2 * M_DIM, 256, 0, stream>>>(wa, wb, pa, pb);
    transpose_conv_kernel<<<dim3(N_DIM / 32, K_DIM / 32), dim3(32, 8), 0, stream>>>(prev, pv);
    coef_kernel<<<M_DIM / 256, 256, 0, stream>>>(tw, coef);
    dual_gemm_kernel<<<dim3(N_DIM / BN, M_DIM / BM), 256, 0, stream>>>(pa, pb, pv, coef, out);
}

// Round 7
// 163.359 us; speedup vs baseline: 1.0318x; 1.0318x over previous
//
#include <hip/hip_runtime.h>
#include <hip/hip_bf16.h>

#define K_DIM 1024
#define M_DIM 4096
#define N_DIM 8192
#define BK 32
#define BM 128
#define BN 128
#define NT 32                      // 1024 / 32 K-tiles

// per-buffer byte offsets (one buffer = A 8K + B 8K + P 8K = 24 KB)
#define OFF_A 0
#define OFF_B 8192
#define OFF_P 16384
#define BUF_BYTES 24576

typedef __attribute__((ext_vector_type(8))) __bf16 bf16x8_t;
typedef __attribute__((ext_vector_type(4))) float f32x4;

#define SBAR do { __builtin_amdgcn_sched_barrier(0); \
                  __builtin_amdgcn_s_barrier(); \
                  __builtin_amdgcn_sched_barrier(0); } while (0)
#define LGKM0 do { asm volatile("s_waitcnt lgkmcnt(0)" ::: "memory"); \
                   __builtin_amdgcn_sched_barrier(0); } while (0)
#define VMCNT(n) do { asm volatile("s_waitcnt vmcnt(" #n ")" ::: "memory"); \
                      __builtin_amdgcn_sched_barrier(0); } while (0)

__device__ inline unsigned short f2bf(float f) {
    unsigned u = __float_as_uint(f);
    u += 0x7FFF + ((u >> 16) & 1);   // round-to-nearest-even
    return (unsigned short)(u >> 16);
}

__device__ __forceinline__ void gload_lds16(const void* g, void* l) {
    __builtin_amdgcn_global_load_lds(
        (const __attribute__((address_space(1))) unsigned int*)g,
        (__attribute__((address_space(3))) unsigned int*)l, 16, 0, 0);
}

// softmax over 1024 cols for wa (blocks 0..4095) and wb (blocks 4096..8191)
__global__ void dual_softmax_kernel(const float* __restrict__ wa,
                                    const float* __restrict__ wb,
                                    unsigned short* __restrict__ pa,
                                    unsigned short* __restrict__ pb) {
    const int idx = blockIdx.x;
    const float* w = (idx < M_DIM) ? wa : wb;
    unsigned short* o = (idx < M_DIM) ? pa : pb;
    const int row = idx & (M_DIM - 1);
    const int tid = threadIdx.x;
    const float4 v = reinterpret_cast<const float4*>(w + (size_t)row * K_DIM)[tid];
    float m = fmaxf(fmaxf(v.x, v.y), fmaxf(v.z, v.w));
    #pragma unroll
    for (int off = 32; off >= 1; off >>= 1) m = fmaxf(m, __shfl_xor(m, off));
    __shared__ float redm[4];
    __shared__ float reds[4];
    if ((tid & 63) == 0) redm[tid >> 6] = m;
    __syncthreads();
    m = fmaxf(fmaxf(redm[0], redm[1]), fmaxf(redm[2], redm[3]));
    const float e0 = __expf(v.x - m), e1 = __expf(v.y - m);
    const float e2 = __expf(v.z - m), e3 = __expf(v.w - m);
    float s = e0 + e1 + e2 + e3;
    #pragma unroll
    for (int off = 32; off >= 1; off >>= 1) s += __shfl_xor(s, off);
    if ((tid & 63) == 0) reds[tid >> 6] = s;
    __syncthreads();
    s = reds[0] + reds[1] + reds[2] + reds[3];
    const float inv = 1.0f / s;
    ushort4 r;
    r.x = f2bf(e0 * inv); r.y = f2bf(e1 * inv);
    r.z = f2bf(e2 * inv); r.w = f2bf(e3 * inv);
    reinterpret_cast<ushort4*>(o + (size_t)row * K_DIM)[tid] = r;
}

// prev (K x N, f32) -> prevT (N x K, bf16)
__global__ void transpose_conv_kernel(const float* __restrict__ src,
                                      unsigned short* __restrict__ dst) {
    __shared__ float t[32][33];
    const int n0 = blockIdx.x * 32;
    const int k0 = blockIdx.y * 32;
    const int tx = threadIdx.x, ty = threadIdx.y;   // 32 x 8
    #pragma unroll
    for (int i = ty; i < 32; i += 8)
        t[i][tx] = src[(size_t)(k0 + i) * N_DIM + n0 + tx];
    __syncthreads();
    #pragma unroll
    for (int i = ty; i < 32; i += 8)
        dst[(size_t)(n0 + i) * K_DIM + k0 + tx] = f2bf(t[tx][i]);
}

__global__ void coef_kernel(const float* __restrict__ tw,
                            float4* __restrict__ coef) {
    const int r = blockIdx.x * 256 + threadIdx.x;
    float p[16];
    float m = -1e30f;
    #pragma unroll
    for (int k = 0; k < 16; ++k) { p[k] = tw[k * M_DIM + r]; m = fmaxf(m, p[k]); }
    float s = 0.f;
    #pragma unroll
    for (int k = 0; k < 16; ++k) { p[k] = __expf(p[k] - m); s += p[k]; }
    const float inv = 1.f / s;
    #pragma unroll
    for (int k = 0; k < 16; ++k) p[k] *= inv;
    const float cA  = p[2]+p[3]+p[6]+p[7]-p[8]-p[9]-p[12]-p[13];
    const float cB  = p[4]+p[5]+p[6]+p[7]-p[8]-p[9]-p[10]-p[11];
    const float cAB = p[1]-p[2]-p[4]-2.f*p[6]-p[7]+p[8]+2.f*p[9]+p[11]+p[13]-p[14];
    const float c0  = p[8]+p[9]+p[10]+p[11]+p[12]+p[13]+p[14]+p[15];
    coef[r] = make_float4(cA, cB, cAB, c0);
}

// Fused dual GEMM. 128x128 tile, 4 waves (2x2, 64x64 each), 16x16x32 MFMA,
// BK=32, TRIPLE-buffered LDS (72 KB) -> 2 blocks/CU co-resident (m114), plus
// counted-vmcnt 2-deep staging pipeline (T4): at iter t issue stage(t+2),
// VMCNT(6) after MFMA waits only stage(t+1) (issued a full iter earlier).
// Swizzle (64-B rows): LDS(row,c16) = G(row, c16 ^ ((row>>1)&3)); frag reads
// apply the same XOR -> 2 lanes/bank-group per 16-lane group (free, m136).
__global__ __launch_bounds__(256, 2)
void dual_gemm_kernel(const unsigned short* __restrict__ pa,
                      const unsigned short* __restrict__ pb,
                      const unsigned short* __restrict__ pv,
                      const float4* __restrict__ coef,
                      float* __restrict__ out) {
    __shared__ unsigned short lds[3 * BUF_BYTES / 2];   // 72 KB

    const int tid = threadIdx.x;
    const int lane = tid & 63;
    const int w = tid >> 6;            // 0..3
    const int wm = w >> 1, wn = w & 1; // 2x2 wave grid, 64x64 each
    const int bm = blockIdx.y, bn = blockIdx.x;

    // staging: chunk = 16 rows x 64 B = 1024 B; 8 chunks/operand; wave owns 2.
    // lane l -> row = chunk*16 + (l>>2), lds col16 = l&3,
    // src col16 = (l&3) ^ ((l>>3)&3)  ( == (l&3) ^ ((row>>1)&3) ).
    const int sub  = lane >> 2;                    // 0..15
    const int scol = (lane & 3) ^ ((lane >> 3) & 3);

    const int c0 = w * 2, c1 = w * 2 + 1;          // this wave's chunks
    const char* sA0 = (const char*)pa + ((size_t)(bm * BM + c0 * 16 + sub) * K_DIM) * 2 + scol * 16;
    const char* sA1 = (const char*)pa + ((size_t)(bm * BM + c1 * 16 + sub) * K_DIM) * 2 + scol * 16;
    const char* sB0 = (const char*)pb + ((size_t)(bm * BM + c0 * 16 + sub) * K_DIM) * 2 + scol * 16;
    const char* sB1 = (const char*)pb + ((size_t)(bm * BM + c1 * 16 + sub) * K_DIM) * 2 + scol * 16;
    const char* sP0 = (const char*)pv + ((size_t)(bn * BN + c0 * 16 + sub) * K_DIM) * 2 + scol * 16;
    const char* sP1 = (const char*)pv + ((size_t)(bn * BN + c1 * 16 + sub) * K_DIM) * 2 + scol * 16;

    const int fr  = lane & 15;
    const int fk  = lane >> 4;         // 0..3 (16B col slot within BK=32 row)
    const int arow0 = wm * 64 + fr;
    const int prow0 = wn * 64 + fr;

    f32x4 accA[4][4], accB[4][4];
    const f32x4 z = {0.f, 0.f, 0.f, 0.f};
    #pragma unroll
    for (int i = 0; i < 4; ++i)
        #pragma unroll
        for (int j = 0; j < 4; ++j) { accA[i][j] = z; accB[i][j] = z; }

    // issue 6 staging loads into buffer at byte offset bo, advance pointers
    #define STAGE_ALL(bo) do {                                              \
        char* base = (char*)lds + (bo);                                     \
        gload_lds16(sA0, base + OFF_A + c0 * 1024);                         \
        gload_lds16(sA1, base + OFF_A + c1 * 1024);                         \
        gload_lds16(sB0, base + OFF_B + c0 * 1024);                         \
        gload_lds16(sB1, base + OFF_B + c1 * 1024);                         \
        gload_lds16(sP0, base + OFF_P + c0 * 1024);                         \
        gload_lds16(sP1, base + OFF_P + c1 * 1024);                         \
        sA0 += BK * 2; sA1 += BK * 2; sB0 += BK * 2; sB1 += BK * 2;         \
        sP0 += BK * 2; sP1 += BK * 2;                                       \
    } while (0)

    // frag read: byte = row*64 + ((fk ^ ((row>>1)&3)) << 4)
    #define READ_FRAGS(bo)                                                   \
        bf16x8_t af[4], bfv[4], pf[4];                                       \
        {                                                                    \
            const char* base = (const char*)lds + (bo);                      \
            _Pragma("unroll")                                                \
            for (int mi = 0; mi < 4; ++mi) {                                 \
                const int row = arow0 + mi * 16;                             \
                const int byte = row * 64 + ((fk ^ ((row >> 1) & 3)) << 4);  \
                af[mi]  = *reinterpret_cast<const bf16x8_t*>(base + OFF_A + byte); \
                bfv[mi] = *reinterpret_cast<const bf16x8_t*>(base + OFF_B + byte); \
            }                                                                \
            _Pragma("unroll")                                                \
            for (int ni = 0; ni < 4; ++ni) {                                 \
                const int row = prow0 + ni * 16;                             \
                const int byte = row * 64 + ((fk ^ ((row >> 1) & 3)) << 4);  \
                pf[ni] = *reinterpret_cast<const bf16x8_t*>(base + OFF_P + byte); \
            }                                                                \
        }

    #define MFMA_ALL do {                                                    \
        __builtin_amdgcn_s_setprio(1);                                       \
        _Pragma("unroll")                                                    \
        for (int mi = 0; mi < 4; ++mi)                                       \
            _Pragma("unroll")                                                \
            for (int ni = 0; ni < 4; ++ni) {                                 \
                accA[mi][ni] = __builtin_amdgcn_mfma_f32_16x16x32_bf16(      \
                    af[mi], pf[ni], accA[mi][ni], 0, 0, 0);                  \
                accB[mi][ni] = __builtin_amdgcn_mfma_f32_16x16x32_bf16(      \
                    bfv[mi], pf[ni], accB[mi][ni], 0, 0, 0);                 \
            }                                                                \
        __builtin_amdgcn_s_setprio(0);                                       \
    } while (0)

    // prologue: stage tiles 0 and 1; wait tile 0 (tile 1 rides, 6 in flight)
    STAGE_ALL(0);
    STAGE_ALL(BUF_BYTES);
    VMCNT(6);
    SBAR;

    int curb = 0, stgb = 2 * BUF_BYTES;
    for (int t = 0; t < NT - 2; ++t) {
        STAGE_ALL(stgb);               // tile t+2 (6 loads)
        READ_FRAGS(curb);              // tile t   (12 ds_read_b128)
        LGKM0;
        MFMA_ALL;
        VMCNT(6);                      // waits tile t+1 (issued last iter)
        SBAR;                          // tile t+1 visible; buf(stg next) free
        stgb = curb;
        curb = (curb == 2 * BUF_BYTES) ? 0 : curb + BUF_BYTES;
    }
    // t = NT-2: nothing to stage; drain last tile fully before final iter
    {
        READ_FRAGS(curb);
        LGKM0;
        MFMA_ALL;
        VMCNT(0);                      // tile NT-1 landed
        SBAR;
        curb = (curb == 2 * BUF_BYTES) ? 0 : curb + BUF_BYTES;
    }
    // t = NT-1
    {
        READ_FRAGS(curb);
        LGKM0;
        MFMA_ALL;
    }

    // epilogue: D layout col=lane&15, row=(lane>>4)*4+reg
    const int row_grp = lane >> 4;
    #pragma unroll
    for (int mi = 0; mi < 4; ++mi) {
        #pragma unroll
        for (int ni = 0; ni < 4; ++ni) {
            const int gr0 = bm * BM + wm * 64 + mi * 16 + row_grp * 4;
            const int gc  = bn * BN + wn * 64 + ni * 16 + (lane & 15);
            #pragma unroll
            for (int i = 0; i < 4; ++i) {
                const int r = gr0 + i;
                const float4 cf = coef[r];
                const float av = accA[mi][ni][i];
                const float bv = accB[mi][ni][i];
                out[(size_t)r * N_DIM + gc] =
                    fmaf(cf.z, av * bv, fmaf(cf.x, av, fmaf(cf.y, bv, cf.w)));
            }
        }
    }
}

extern "C" void kernel_launch(void* const* d_in, const int* in_sizes, int n_in,
                              void* d_out, int out_size, void* d_ws, size_t ws_size,
                              hipStream_t stream) {
    const float* prev = (const float*)d_in[0];   // (1024, 8192)
    const float* wa   = (const float*)d_in[1];   // (4096, 1024)
    const float* wb   = (const float*)d_in[2];   // (4096, 1024)
    const float* tw   = (const float*)d_in[3];   // (16, 4096)
    float* out = (float*)d_out;                  // (4096, 8192)

    char* ws = (char*)d_ws;
    unsigned short* pa = (unsigned short*)ws;                        // 8 MB
    unsigned short* pb = (unsigned short*)(ws + 8388608);            // 8 MB
    unsigned short* pv = (unsigned short*)(ws + 16777216);           // 16 MB
    float4* coef       = (float4*)(ws + 33554432);                   // 64 KB

    dual_softmax_kernel<<<2 * M_DIM, 256, 0, stream>>>(wa, wb, pa, pb);
    transpose_conv_kernel<<<dim3(N_DIM / 32, K_DIM / 32), dim3(32, 8), 0, stream>>>(prev, pv);
    coef_kernel<<<M_DIM / 256, 256, 0, stream>>>(tw, coef);
    dual_gemm_kernel<<<dim3(N_DIM / BN, M_DIM / BM), 256, 0, stream>>>(pa, pb, pv, coef, out);
}

// Round 8
// 155.803 us; speedup vs baseline: 1.0818x; 1.0485x over previous
//
#include <hip/hip_runtime.h>
#include <hip/hip_bf16.h>

#define K_DIM 1024
#define M_DIM 4096
#define N_DIM 8192
#define BK 64
#define BM 128
#define BN 256
#define NT 16

#define OFF_A 0
#define OFF_B 16384                      // bytes
#define OFF_P 32768
#define BUF_BYTES 65536                  // A 16K + B 16K + P 32K

typedef __attribute__((ext_vector_type(8))) __bf16 bf16x8_t;
typedef __attribute__((ext_vector_type(4))) float f32x4;

#define SBAR __builtin_amdgcn_s_barrier()
#define LGKM0 asm volatile("s_waitcnt lgkmcnt(0)" ::: "memory")
#define VMCNT0 asm volatile("s_waitcnt vmcnt(0)" ::: "memory")

__device__ inline unsigned short f2bf(float f) {
    unsigned u = __float_as_uint(f);
    u += 0x7FFF + ((u >> 16) & 1);   // round-to-nearest-even
    return (unsigned short)(u >> 16);
}

__device__ __forceinline__ void gload_lds16(const void* g, void* l) {
    __builtin_amdgcn_global_load_lds(
        (const __attribute__((address_space(1))) unsigned int*)g,
        (__attribute__((address_space(3))) unsigned int*)l, 16, 0, 0);
}

// softmax over 1024 cols for wa (blocks 0..4095) and wb (blocks 4096..8191)
__global__ void dual_softmax_kernel(const float* __restrict__ wa,
                                    const float* __restrict__ wb,
                                    unsigned short* __restrict__ pa,
                                    unsigned short* __restrict__ pb) {
    const int idx = blockIdx.x;
    const float* w = (idx < M_DIM) ? wa : wb;
    unsigned short* o = (idx < M_DIM) ? pa : pb;
    const int row = idx & (M_DIM - 1);
    const int tid = threadIdx.x;
    const float4 v = reinterpret_cast<const float4*>(w + (size_t)row * K_DIM)[tid];
    float m = fmaxf(fmaxf(v.x, v.y), fmaxf(v.z, v.w));
    #pragma unroll
    for (int off = 32; off >= 1; off >>= 1) m = fmaxf(m, __shfl_xor(m, off));
    __shared__ float redm[4];
    __shared__ float reds[4];
    if ((tid & 63) == 0) redm[tid >> 6] = m;
    __syncthreads();
    m = fmaxf(fmaxf(redm[0], redm[1]), fmaxf(redm[2], redm[3]));
    const float e0 = __expf(v.x - m), e1 = __expf(v.y - m);
    const float e2 = __expf(v.z - m), e3 = __expf(v.w - m);
    float s = e0 + e1 + e2 + e3;
    #pragma unroll
    for (int off = 32; off >= 1; off >>= 1) s += __shfl_xor(s, off);
    if ((tid & 63) == 0) reds[tid >> 6] = s;
    __syncthreads();
    s = reds[0] + reds[1] + reds[2] + reds[3];
    const float inv = 1.0f / s;
    ushort4 r;
    r.x = f2bf(e0 * inv); r.y = f2bf(e1 * inv);
    r.z = f2bf(e2 * inv); r.w = f2bf(e3 * inv);
    reinterpret_cast<ushort4*>(o + (size_t)row * K_DIM)[tid] = r;
}

// prev (K x N, f32) -> prevT (N x K, bf16)
__global__ void transpose_conv_kernel(const float* __restrict__ src,
                                      unsigned short* __restrict__ dst) {
    __shared__ float t[32][33];
    const int n0 = blockIdx.x * 32;
    const int k0 = blockIdx.y * 32;
    const int tx = threadIdx.x, ty = threadIdx.y;   // 32 x 8
    #pragma unroll
    for (int i = ty; i < 32; i += 8)
        t[i][tx] = src[(size_t)(k0 + i) * N_DIM + n0 + tx];
    __syncthreads();
    #pragma unroll
    for (int i = ty; i < 32; i += 8)
        dst[(size_t)(n0 + i) * K_DIM + k0 + tx] = f2bf(t[tx][i]);
}

__global__ void coef_kernel(const float* __restrict__ tw,
                            float4* __restrict__ coef) {
    const int r = blockIdx.x * 256 + threadIdx.x;
    float p[16];
    float m = -1e30f;
    #pragma unroll
    for (int k = 0; k < 16; ++k) { p[k] = tw[k * M_DIM + r]; m = fmaxf(m, p[k]); }
    float s = 0.f;
    #pragma unroll
    for (int k = 0; k < 16; ++k) { p[k] = __expf(p[k] - m); s += p[k]; }
    const float inv = 1.f / s;
    #pragma unroll
    for (int k = 0; k < 16; ++k) p[k] *= inv;
    const float cA  = p[2]+p[3]+p[6]+p[7]-p[8]-p[9]-p[12]-p[13];
    const float cB  = p[4]+p[5]+p[6]+p[7]-p[8]-p[9]-p[10]-p[11];
    const float cAB = p[1]-p[2]-p[4]-2.f*p[6]-p[7]+p[8]+2.f*p[9]+p[11]+p[13]-p[14];
    const float c0  = p[8]+p[9]+p[10]+p[11]+p[12]+p[13]+p[14]+p[15];
    coef[r] = make_float4(cA, cB, cAB, c0);
}

__device__ __forceinline__ void load_frags4(const unsigned short* lbase, int row0,
                                            int fk16, bf16x8_t (&f)[4]) {
    #pragma unroll
    for (int i = 0; i < 4; ++i) {
        const int row = row0 + i * 16;
        f[i] = *reinterpret_cast<const bf16x8_t*>(
            (const char*)lbase + row * 128 + ((fk16 ^ (row & 7)) * 16));
    }
}

__device__ __forceinline__ void mfma_block(const bf16x8_t (&a)[4], const bf16x8_t (&p)[4],
                                           f32x4 (&acc)[4][4]) {
    __builtin_amdgcn_s_setprio(1);
    #pragma unroll
    for (int mi = 0; mi < 4; ++mi)
        #pragma unroll
        for (int ni = 0; ni < 4; ++ni)
            acc[mi][ni] = __builtin_amdgcn_mfma_f32_16x16x32_bf16(
                a[mi], p[ni], acc[mi][ni], 0, 0, 0);
    __builtin_amdgcn_s_setprio(0);
}

// Fused dual GEMM, 8-wave 128x256 tile, BK=64, double-buffered LDS (128 KB).
// m201-discipline 4-phase schedule: per phase {C++ ds_reads; stage-issue;
// s_barrier; bare lgkmcnt(0); setprio MFMA x16 setprio; s_barrier} with NO
// sched_barriers (the compiler's own dep-tracking orders C++ reads vs MFMA;
// fences were defeating its fine-grained scheduling - m141 failure mode).
// Staging issue plan (loads for tile t+1): P1: B'(2); P2: A'(2)+P'(4);
// P4: vmcnt(0) [everything has >=2-phase (~1400 cy) cover] then barrier ->
// next-P1 reads are safe. One drain per K-tile, always cover-protected.
__global__ __launch_bounds__(512, 2)
void dual_gemm_kernel(const unsigned short* __restrict__ pa,
                      const unsigned short* __restrict__ pb,
                      const unsigned short* __restrict__ pv,
                      const float4* __restrict__ coef,
                      float* __restrict__ out) {
    __shared__ unsigned short lds[2 * BUF_BYTES / 2];   // 128 KB

    const int tid = threadIdx.x;
    const int lane = tid & 63;
    const int w = tid >> 6;            // 0..7
    const int wm = w >> 2, wn = w & 3; // 2 (M) x 4 (N), 64x64 each
    const int bm = blockIdx.y, bn = blockIdx.x;

    const int sub_row = lane >> 3;                // 0..7
    const int scol16  = (lane & 7) ^ sub_row;     // pre-swizzled src 16B col

    const unsigned short* gA = pa + (size_t)(bm * BM) * K_DIM;
    const unsigned short* gB = pb + (size_t)(bm * BM) * K_DIM;
    const unsigned short* gP = pv + (size_t)(bn * BN) * K_DIM;

    const int fr  = lane & 15;
    const int fkb = lane >> 4;         // 0..3 (16B col in K-row)
    const int arow0 = wm * 64 + fr;
    const int prow0 = wn * 64 + fr;

    f32x4 accA[4][4], accB[4][4];
    const f32x4 z = {0.f, 0.f, 0.f, 0.f};
    #pragma unroll
    for (int i = 0; i < 4; ++i)
        #pragma unroll
        for (int j = 0; j < 4; ++j) { accA[i][j] = z; accB[i][j] = z; }

    auto stage = [&](const unsigned short* gbase, int lds_byte_off, int chunk, int k) {
        const int r = chunk * 8 + sub_row;
        const char* src = (const char*)(gbase + (size_t)r * K_DIM + k) + scol16 * 16;
        char* dst = (char*)lds + lds_byte_off + chunk * 1024;
        gload_lds16(src, dst);
    };

    // prologue: stage tile 0 into buffer 0, drain, barrier
    stage(gB, OFF_B, 2 * w, 0);     stage(gB, OFF_B, 2 * w + 1, 0);
    stage(gA, OFF_A, 2 * w, 0);     stage(gA, OFF_A, 2 * w + 1, 0);
    stage(gP, OFF_P, 4 * w, 0);     stage(gP, OFF_P, 4 * w + 1, 0);
    stage(gP, OFF_P, 4 * w + 2, 0); stage(gP, OFF_P, 4 * w + 3, 0);
    VMCNT0;
    SBAR;

    for (int t = 0; t < NT - 1; ++t) {
        const int kn = (t + 1) * BK;
        const int co = (t & 1) * BUF_BYTES;
        const int no = co ^ BUF_BYTES;
        const unsigned short* cb = (const unsigned short*)((const char*)lds + co);
        bf16x8_t af0[4], pf0[4], bf0[4], af1[4], pf1[4], bf1[4];

        // ---- P1: accA kk0 ----
        load_frags4((const unsigned short*)((const char*)cb + OFF_A), arow0, fkb, af0);
        load_frags4((const unsigned short*)((const char*)cb + OFF_P), prow0, fkb, pf0);
        stage(gB, no + OFF_B, 2 * w, kn); stage(gB, no + OFF_B, 2 * w + 1, kn);
        SBAR;
        LGKM0;
        mfma_block(af0, pf0, accA);
        SBAR;

        // ---- P2: accB kk0 (reuses pf0) ----
        load_frags4((const unsigned short*)((const char*)cb + OFF_B), arow0, fkb, bf0);
        stage(gA, no + OFF_A, 2 * w, kn); stage(gA, no + OFF_A, 2 * w + 1, kn);
        stage(gP, no + OFF_P, 4 * w, kn); stage(gP, no + OFF_P, 4 * w + 1, kn);
        stage(gP, no + OFF_P, 4 * w + 2, kn); stage(gP, no + OFF_P, 4 * w + 3, kn);
        SBAR;
        LGKM0;
        mfma_block(bf0, pf0, accB);
        SBAR;

        // ---- P3: accA kk1 ----
        load_frags4((const unsigned short*)((const char*)cb + OFF_A), arow0, fkb + 4, af1);
        load_frags4((const unsigned short*)((const char*)cb + OFF_P), prow0, fkb + 4, pf1);
        SBAR;
        LGKM0;
        mfma_block(af1, pf1, accA);
        SBAR;

        // ---- P4: accB kk1; cover-protected drain of next tile's loads ----
        load_frags4((const unsigned short*)((const char*)cb + OFF_B), arow0, fkb + 4, bf1);
        VMCNT0;        // B' issued P1 (3 phases ago), A'+P' issued P2 (2 phases)
        SBAR;
        LGKM0;
        mfma_block(bf1, pf1, accB);
        SBAR;          // staged tile t+1 now visible to all waves
    }

    // ---- tail tile (t = NT-1, buffer 1): no staging, no barriers ----
    {
        const unsigned short* cb =
            (const unsigned short*)((const char*)lds + ((NT - 1) & 1) * BUF_BYTES);
        bf16x8_t af0[4], pf0[4], bf0[4], af1[4], pf1[4], bf1[4];
        load_frags4((const unsigned short*)((const char*)cb + OFF_A), arow0, fkb, af0);
        load_frags4((const unsigned short*)((const char*)cb + OFF_P), prow0, fkb, pf0);
        mfma_block(af0, pf0, accA);
        load_frags4((const unsigned short*)((const char*)cb + OFF_B), arow0, fkb, bf0);
        mfma_block(bf0, pf0, accB);
        load_frags4((const unsigned short*)((const char*)cb + OFF_A), arow0, fkb + 4, af1);
        load_frags4((const unsigned short*)((const char*)cb + OFF_P), prow0, fkb + 4, pf1);
        mfma_block(af1, pf1, accA);
        load_frags4((const unsigned short*)((const char*)cb + OFF_B), arow0, fkb + 4, bf1);
        mfma_block(bf1, pf1, accB);
    }

    // epilogue: D layout col=lane&15, row=(lane>>4)*4+reg
    const int row_grp = lane >> 4;
    #pragma unroll
    for (int mi = 0; mi < 4; ++mi) {
        #pragma unroll
        for (int ni = 0; ni < 4; ++ni) {
            const int gr0 = bm * BM + wm * 64 + mi * 16 + row_grp * 4;
            const int gc  = bn * BN + wn * 64 + ni * 16 + (lane & 15);
            #pragma unroll
            for (int i = 0; i < 4; ++i) {
                const int r = gr0 + i;
                const float4 cf = coef[r];
                const float av = accA[mi][ni][i];
                const float bv = accB[mi][ni][i];
                out[(size_t)r * N_DIM + gc] =
                    fmaf(cf.z, av * bv, fmaf(cf.x, av, fmaf(cf.y, bv, cf.w)));
            }
        }
    }
}

extern "C" void kernel_launch(void* const* d_in, const int* in_sizes, int n_in,
                              void* d_out, int out_size, void* d_ws, size_t ws_size,
                              hipStream_t stream) {
    const float* prev = (const float*)d_in[0];   // (1024, 8192)
    const float* wa   = (const float*)d_in[1];   // (4096, 1024)
    const float* wb   = (const float*)d_in[2];   // (4096, 1024)
    const float* tw   = (const float*)d_in[3];   // (16, 4096)
    float* out = (float*)d_out;                  // (4096, 8192)

    char* ws = (char*)d_ws;
    unsigned short* pa = (unsigned short*)ws;                        // 8 MB
    unsigned short* pb = (unsigned short*)(ws + 8388608);            // 8 MB
    unsigned short* pv = (unsigned short*)(ws + 16777216);           // 16 MB
    float4* coef       = (float4*)(ws + 33554432);                   // 64 KB

    dual_softmax_kernel<<<2 * M_DIM, 256, 0, stream>>>(wa, wb, pa, pb);
    transpose_conv_kernel<<<dim3(N_DIM / 32, K_DIM / 32), dim3(32, 8), 0, stream>>>(prev, pv);
    coef_kernel<<<M_DIM / 256, 256, 0, stream>>>(tw, coef);
    dual_gemm_kernel<<<dim3(N_DIM / BN, M_DIM / BM), 512, 0, stream>>>(pa, pb, pv, coef, out);
}